// Round 10
// baseline (354.524 us; speedup 1.0000x reference)
//
#include <hip/hip_runtime.h>
#include <hip/hip_bf16.h>
#include <stdint.h>

// TransformerEncoderLayer: B=4, S=1024, D=1024, H=16, DK=64, F=4096, fp32 io.
// Round 8 (resubmit x2): attn = round-6 tiles (KVBLK=64, 40KB LDS, 0-conflict)
// + round-7 fast softmax (exp2-fma unscaled-domain, defer-max, rcp), LB(256,4).
// pack_bias folded into gemm256<0>. GEMMs unchanged.
// Workspace (bytes), peak = 92286976:
//   [0,        6291456)  wqkvT bf16 [3072][1024]
//   [6291456,  8388608)  woT   bf16 [1024][1024]
//   [8388608, 16777216)  w1T   bf16 [4096][1024]
//   [16777216,25165824)  w2T   bf16 [1024][4096]
//   [25178112,33566720)  xbf   bf16 [4096][1024] (→ctxb; later f2_p1 overlaps)
//   [33566720,58732544)  qkv   bf16 3x[B,H,S,DK] (→mh_p1 @33.56, h1b @50.34)
//   [58732544,92286976)  f1b   bf16 [4096][4096]
//   d_out: vt during attention; mh_p0/f2_p0 fp32 afterwards; final out.

typedef __bf16 bf16x8 __attribute__((ext_vector_type(8)));
typedef __bf16 bf16x4 __attribute__((ext_vector_type(4)));
typedef float f32x4 __attribute__((ext_vector_type(4)));

__device__ __forceinline__ f32x4 mfma16(bf16x8 a, bf16x8 b, f32x4 c) {
  return __builtin_amdgcn_mfma_f32_16x16x32_bf16(a, b, c, 0, 0, 0);
}

__device__ __forceinline__ void gload_lds16(const void* g, void* l) {
  typedef const unsigned int __attribute__((address_space(1)))* GP;
  typedef unsigned int __attribute__((address_space(3)))* LP;
  __builtin_amdgcn_global_load_lds((GP)(uintptr_t)g,
                                   (LP)(unsigned int)(uintptr_t)l, 16, 0, 0);
}

// ---------------------------------------------------------------------------
// gemm256: 256x256 tile, BK=64, 512 thr (8 waves = 2M x 4N, each 128x64 out).
// Proven round 5. EPI 0: QKV scatter bf16, bias from bq/bk/bv by proj.
// EPI 1: relu->bf16 row-major, bias from b1.
// ---------------------------------------------------------------------------
template <int EPI>
__global__ __launch_bounds__(512, 2) void gemm256(
    const __bf16* __restrict__ A, const __bf16* __restrict__ BT,
    const float* __restrict__ bias, const float* __restrict__ biasK,
    const float* __restrict__ biasV, __bf16* __restrict__ Cb,
    int M, int N, int K)
{
  __shared__ __attribute__((aligned(16))) __bf16 lds[2][2][2][8192];
  const int tid = threadIdx.x;
  const int lane = tid & 63;
  const int w = tid >> 6;
  const int l15 = lane & 15, lhi = lane >> 4;

  const int nbx = gridDim.x;
  const int nwg = nbx * gridDim.y;
  const int wid = blockIdx.y * nbx + blockIdx.x;
  const int sw = (wid & 7) * (nwg >> 3) + (wid >> 3);
  const int n0 = (sw % nbx) * 256;
  const int m0 = (sw / nbx) * 256;

  const int mat = w >> 2, halfI = (w >> 1) & 1, sub = w & 1;
  const __bf16* srcM = mat ? BT : A;
  const long rowG = (long)((mat ? n0 : m0) + halfI * 128 + sub * 64 + (lane >> 3));
  const __bf16* gsrc =
      srcM + rowG * K + (((lane & 7) ^ ((lane >> 3) & 7)) << 3);
  const int ldst = sub * 4096 + lane * 8;

  const int owr = w >> 2, owc = w & 3;

  const f32x4 fz = {0.f, 0.f, 0.f, 0.f};
  f32x4 acc[8][4];
#pragma unroll
  for (int i = 0; i < 8; i++)
#pragma unroll
    for (int j = 0; j < 4; j++) acc[i][j] = fz;

  const int KT = K >> 6;
  const int swz = (l15 & 7);

#pragma unroll
  for (int i = 0; i < 8; i++)
    gload_lds16(gsrc + (long)i * 8 * K, &lds[0][mat][halfI][ldst + i * 512]);

  for (int kt = 0; kt < KT; ++kt) {
    const int buf = kt & 1;
    if (kt + 1 < KT) {
#pragma unroll
      for (int i = 0; i < 8; i++)
        gload_lds16(gsrc + (long)(kt + 1) * 64 + (long)i * 8 * K,
                    &lds[buf ^ 1][mat][halfI][ldst + i * 512]);
      asm volatile("s_waitcnt vmcnt(8)" ::: "memory");
    } else {
      asm volatile("s_waitcnt vmcnt(0)" ::: "memory");
    }
    __builtin_amdgcn_s_barrier();
    __builtin_amdgcn_sched_barrier(0);

    const __bf16* Abase = &lds[buf][0][owr][0];
    const __bf16* Bbase = &lds[buf][1][owc >> 1][0];
    const int brow0 = (owc & 1) * 64;

    bf16x8 bfr[4][2];
#pragma unroll
    for (int nf = 0; nf < 4; nf++)
#pragma unroll
      for (int kk = 0; kk < 2; kk++) {
        const int row = brow0 + nf * 16 + l15;
        bfr[nf][kk] =
            *(const bf16x8*)&Bbase[row * 64 + ((((kk << 2) | lhi) ^ swz) << 3)];
      }

#pragma unroll
    for (int q = 0; q < 4; q++) {
      bf16x8 af[2][2];
#pragma unroll
      for (int m2 = 0; m2 < 2; m2++)
#pragma unroll
        for (int kk = 0; kk < 2; kk++) {
          const int row = (q * 2 + m2) * 16 + l15;
          af[m2][kk] =
              *(const bf16x8*)&Abase[row * 64 + ((((kk << 2) | lhi) ^ swz) << 3)];
        }
      __builtin_amdgcn_s_barrier();
      __builtin_amdgcn_s_setprio(1);
#pragma unroll
      for (int m2 = 0; m2 < 2; m2++)
#pragma unroll
        for (int nf = 0; nf < 4; nf++)
#pragma unroll
          for (int kk = 0; kk < 2; kk++)
            acc[q * 2 + m2][nf] =
                mfma16(af[m2][kk], bfr[nf][kk], acc[q * 2 + m2][nf]);
      __builtin_amdgcn_s_setprio(0);
      __builtin_amdgcn_s_barrier();
    }
  }

  if (EPI == 0) {  // QKV scatter; bias selected by proj (wave-uniform per nf)
#pragma unroll
    for (int mi = 0; mi < 8; mi++) {
      const int mB = m0 + owr * 128 + mi * 16 + lhi * 4;
#pragma unroll
      for (int nf = 0; nf < 4; nf++) {
        const int n = n0 + owc * 64 + nf * 16 + l15;
        const int proj = n >> 10, hh = (n >> 6) & 15, dk = n & 63;
        const float* bsrc = proj == 0 ? bias : (proj == 1 ? biasK : biasV);
        const float bs = bsrc[n & 1023];
#pragma unroll
        for (int rr = 0; rr < 4; rr++) {
          const int m = mB + rr;
          const int b = m >> 10, sidx = m & 1023;
          Cb[(long)proj * 4194304 +
             ((long)(b * 16 + hh) * 1024 + sidx) * 64 + dk] =
              (__bf16)(acc[mi][nf][rr] + bs);
        }
      }
    }
  } else {  // relu -> bf16 row-major
#pragma unroll
    for (int mi = 0; mi < 8; mi++) {
      const int mB = m0 + owr * 128 + mi * 16 + lhi * 4;
#pragma unroll
      for (int nf = 0; nf < 4; nf++) {
        const int n = n0 + owc * 64 + nf * 16 + l15;
        const float bs = bias[n];
#pragma unroll
        for (int rr = 0; rr < 4; rr++) {
          float v = acc[mi][nf][rr] + bs;
          v = v > 0.f ? v : 0.f;
          Cb[(long)(mB + rr) * N + n] = (__bf16)v;
        }
      }
    }
  }
}

// ---------------------------------------------------------------------------
// gemm_ksplit: 128x256 tile, BK=64, split-K2, proven round 6.
// ---------------------------------------------------------------------------
__global__ __launch_bounds__(512, 2) void gemm_ksplit(
    const __bf16* __restrict__ A, const __bf16* __restrict__ BT,
    const float* __restrict__ bias, float* __restrict__ Cf0,
    float* __restrict__ Cf1, int M, int N, int ld, int Kh)
{
  __shared__ __attribute__((aligned(16))) __bf16 As[2][8192];
  __shared__ __attribute__((aligned(16))) __bf16 Bs[2][16384];
  const int tid = threadIdx.x;
  const int lane = tid & 63;
  const int w = tid >> 6;
  const int l15 = lane & 15, lhi = lane >> 4;

  const int nbx = gridDim.x;
  const int nby = gridDim.y;
  const int nxy = nbx * nby;
  const int nwg = nxy * 2;
  const int wid = (blockIdx.z * nby + blockIdx.y) * nbx + blockIdx.x;
  const int sw = (wid & 7) * (nwg >> 3) + (wid >> 3);
  const int z = sw / nxy;
  const int rem = sw % nxy;
  const int m0 = (rem / nbx) * 128;
  const int n0 = (rem % nbx) * 256;
  const long zoff = (long)z * Kh;

  const int trow = tid >> 3;
  const int sswz = ((tid & 7) ^ (trow & 7)) << 3;
  const __bf16* gA = A + (long)(m0 + trow) * ld + zoff + sswz;
  const __bf16* gB = BT + (long)(n0 + trow) * ld + zoff + sswz;
  const int ldst = tid * 8;

  const int owr = w >> 2, owc = w & 3;

  const f32x4 fz = {0.f, 0.f, 0.f, 0.f};
  f32x4 acc[4][4];
#pragma unroll
  for (int i = 0; i < 4; i++)
#pragma unroll
    for (int j = 0; j < 4; j++) acc[i][j] = fz;

  const int KT = Kh >> 6;
  const int swz = (l15 & 7);

  {
    gload_lds16(gA, &As[0][ldst]);
    gload_lds16(gA + 64 * (long)ld, &As[0][ldst + 4096]);
    gload_lds16(gB, &Bs[0][ldst]);
    gload_lds16(gB + 64 * (long)ld, &Bs[0][ldst + 4096]);
    gload_lds16(gB + 128 * (long)ld, &Bs[0][ldst + 8192]);
    gload_lds16(gB + 192 * (long)ld, &Bs[0][ldst + 12288]);
  }

  for (int kt = 0; kt < KT; ++kt) {
    const int buf = kt & 1;
    if (kt + 1 < KT) {
      const __bf16* a0 = gA + (kt + 1) * 64;
      const __bf16* b0 = gB + (kt + 1) * 64;
      gload_lds16(a0, &As[buf ^ 1][ldst]);
      gload_lds16(a0 + 64 * (long)ld, &As[buf ^ 1][ldst + 4096]);
      gload_lds16(b0, &Bs[buf ^ 1][ldst]);
      gload_lds16(b0 + 64 * (long)ld, &Bs[buf ^ 1][ldst + 4096]);
      gload_lds16(b0 + 128 * (long)ld, &Bs[buf ^ 1][ldst + 8192]);
      gload_lds16(b0 + 192 * (long)ld, &Bs[buf ^ 1][ldst + 12288]);
      asm volatile("s_waitcnt vmcnt(6)" ::: "memory");
    } else {
      asm volatile("s_waitcnt vmcnt(0)" ::: "memory");
    }
    __builtin_amdgcn_s_barrier();
    __builtin_amdgcn_sched_barrier(0);

    const __bf16* Abase = &As[buf][owr * 4096];
    const __bf16* Bbase = &Bs[buf][owc * 4096];

    bf16x8 bfr[4][2];
#pragma unroll
    for (int nf = 0; nf < 4; nf++)
#pragma unroll
      for (int kk = 0; kk < 2; kk++) {
        const int row = nf * 16 + l15;
        bfr[nf][kk] =
            *(const bf16x8*)&Bbase[row * 64 + ((((kk << 2) | lhi) ^ swz) << 3)];
      }

#pragma unroll
    for (int q = 0; q < 4; q++) {
      bf16x8 af[2];
#pragma unroll
      for (int kk = 0; kk < 2; kk++) {
        const int row = q * 16 + l15;
        af[kk] =
            *(const bf16x8*)&Abase[row * 64 + ((((kk << 2) | lhi) ^ swz) << 3)];
      }
      __builtin_amdgcn_s_barrier();
      __builtin_amdgcn_s_setprio(1);
#pragma unroll
      for (int nf = 0; nf < 4; nf++)
#pragma unroll
        for (int kk = 0; kk < 2; kk++)
          acc[q][nf] = mfma16(af[kk], bfr[nf][kk], acc[q][nf]);
      __builtin_amdgcn_s_setprio(0);
      __builtin_amdgcn_s_barrier();
    }
  }

  float* Cf = z ? Cf1 : Cf0;
#pragma unroll
  for (int mi = 0; mi < 4; mi++) {
    const int mB = m0 + owr * 64 + mi * 16 + lhi * 4;
#pragma unroll
    for (int nf = 0; nf < 4; nf++) {
      const int n = n0 + owc * 64 + nf * 16 + l15;
      const float bs = z ? 0.f : bias[n];
#pragma unroll
      for (int rr = 0; rr < 4; rr++)
        Cf[(long)(mB + rr) * N + n] = acc[mi][nf][rr] + bs;
    }
  }
}

// ---------------------------------------------------------------------------
// V transpose: v [bh][s][dk=64] -> vt [bh][dk][s=1024]. 64x64 LDS tiles.
// ---------------------------------------------------------------------------
__global__ __launch_bounds__(256) void vtrans_kernel(
    const __bf16* __restrict__ in, __bf16* __restrict__ out)
{
  __shared__ __bf16 t[64][66];
  const int bh = blockIdx.y, s0 = blockIdx.x * 64;
  const int tx = threadIdx.x & 63, ty = threadIdx.x >> 6;
  const __bf16* ip = in + (long)bh * 65536 + (long)s0 * 64;
  __bf16* op = out + (long)bh * 65536;
#pragma unroll
  for (int i = 0; i < 64; i += 4) t[ty + i][tx] = ip[(ty + i) * 64 + tx];
  __syncthreads();
#pragma unroll
  for (int i = 0; i < 64; i += 4)
    op[(long)(ty + i) * 1024 + s0 + tx] = t[tx][ty + i];
}

// ---------------------------------------------------------------------------
// Flash attention: round-6 tiles (KVBLK=64, 40KB LDS, measured 0-conflict)
// + fast softmax (exp2-fma unscaled domain, defer-max THR=64, rcp epilogue).
// grid=(S/64, B*H), 256 thr (4 waves), wave owns 16 q-rows.
// ---------------------------------------------------------------------------
__global__ __launch_bounds__(256, 4) void attn_kernel(
    const __bf16* __restrict__ qg_, const __bf16* __restrict__ kg_,
    const __bf16* __restrict__ vtg_, __bf16* __restrict__ ctx)
{
  __shared__ __attribute__((aligned(16))) __bf16 Kb[2][64 * 64];
  __shared__ __attribute__((aligned(16))) __bf16 Vb[2][64 * 64];
  __shared__ __attribute__((aligned(16))) __bf16 Ps[4][16 * 64];
  const int tid = threadIdx.x, lane = tid & 63, w = tid >> 6;
  const int l15 = lane & 15, lhi = lane >> 4;
  const int bh = blockIdx.y;
  const int b = bh >> 4, h = bh & 15;
  const int q0 = blockIdx.x * 64 + w * 16;

  const __bf16* qg = qg_ + ((long)bh * 1024 + q0) * 64;
  const __bf16* kg = kg_ + (long)bh * 65536;   // [s][64]
  const __bf16* vtg = vtg_ + (long)bh * 65536; // [dk][1024]

  bf16x8 qa[2];
  qa[0] = *(const bf16x8*)&qg[l15 * 64 + lhi * 8];
  qa[1] = *(const bf16x8*)&qg[l15 * 64 + 32 + lhi * 8];

  const int srow0 = tid >> 3;
  const int srow1 = srow0 + 32;
  const int sw0 = (tid & 7) ^ (srow0 & 7);
  const int sw1 = (tid & 7) ^ (srow1 & 7);
  const __bf16* kst0 = kg + srow0 * 64 + sw0 * 8;
  const __bf16* kst1 = kg + srow1 * 64 + sw1 * 8;
  const __bf16* vst0 = vtg + srow0 * 1024 + sw0 * 8;
  const __bf16* vst1 = vtg + srow1 * 1024 + sw1 * 8;

  const f32x4 fz = {0.f, 0.f, 0.f, 0.f};
  float mrun[4], lrun[4];
  f32x4 o[4];
#pragma unroll
  for (int r = 0; r < 4; r++) { mrun[r] = -1e30f; lrun[r] = 0.f; }
#pragma unroll
  for (int n = 0; n < 4; n++) o[n] = fz;

  const int e = l15 & 7;
  const int c0 = (lhi ^ e) * 8;
  const int c1 = ((4 | lhi) ^ e) * 8;
  const float csc = 0.18033688f;  // 0.125 * log2(e)

  {
    __bf16* kb = &Kb[0][tid * 8];
    __bf16* vb = &Vb[0][tid * 8];
    gload_lds16(kst0, kb);
    gload_lds16(kst1, kb + 2048);
    gload_lds16(vst0, vb);
    gload_lds16(vst1, vb + 2048);
  }

  int cur = 0;
  for (int t = 0; t < 16; ++t) {
    __syncthreads();  // buf[cur] staged (drains vmcnt); buf[cur^1] reads done
    if (t + 1 < 16) {
      __bf16* kb = &Kb[cur ^ 1][tid * 8];
      __bf16* vb = &Vb[cur ^ 1][tid * 8];
      gload_lds16(kst0 + (t + 1) * 4096, kb);
      gload_lds16(kst1 + (t + 1) * 4096, kb + 2048);
      gload_lds16(vst0 + (t + 1) * 64, vb);
      gload_lds16(vst1 + (t + 1) * 64, vb + 2048);
    }

    // S = Q K^T (wave: 16 q x 64 kv)
    f32x4 s[4];
#pragma unroll
    for (int n = 0; n < 4; n++) s[n] = fz;
    __builtin_amdgcn_s_setprio(1);
#pragma unroll
    for (int n = 0; n < 4; n++) {
      const int row = (n * 16 + l15) * 64;
      bf16x8 kb0 = *(const bf16x8*)&Kb[cur][row + c0];
      bf16x8 kb1 = *(const bf16x8*)&Kb[cur][row + c1];
      s[n] = mfma16(qa[0], kb0, s[n]);
      s[n] = mfma16(qa[1], kb1, s[n]);
    }
    __builtin_amdgcn_s_setprio(0);

    // row max (unscaled domain)
    float mx[4];
#pragma unroll
    for (int r = 0; r < 4; r++) {
      float m = fmaxf(fmaxf(s[0][r], s[1][r]), fmaxf(s[2][r], s[3][r]));
#pragma unroll
      for (int off = 8; off; off >>= 1) m = fmaxf(m, __shfl_xor(m, off));
      mx[r] = m;
    }
    // defer-max: rescale only if any row grew by >64 (e^8 after scaling)
    bool need = false;
#pragma unroll
    for (int r = 0; r < 4; r++) need = need || (mx[r] > mrun[r] + 64.f);
    if (__any(need)) {
#pragma unroll
      for (int r = 0; r < 4; r++) {
        const float mnew = fmaxf(mrun[r], mx[r]);
        const float alpha = __builtin_amdgcn_exp2f((mrun[r] - mnew) * csc);
        mrun[r] = mnew;
        lrun[r] *= alpha;
#pragma unroll
        for (int n = 0; n < 4; n++) o[n][r] *= alpha;
      }
    }
    // P = exp2((s - m) * c), row sums
    float p[4][4];
#pragma unroll
    for (int r = 0; r < 4; r++) {
      const float mc = mrun[r] * csc;
      float ps = 0.f;
#pragma unroll
      for (int n = 0; n < 4; n++) {
        const float pv =
            __builtin_amdgcn_exp2f(__builtin_fmaf(s[n][r], csc, -mc));
        p[n][r] = pv;
        ps += pv;
      }
#pragma unroll
      for (int off = 8; off; off >>= 1) ps += __shfl_xor(ps, off);
      lrun[r] += ps;
    }

    // P -> LDS (swizzled), re-read as A frags
#pragma unroll
    for (int n = 0; n < 4; n++) {
      const int ch = n * 2 + (l15 >> 3);
#pragma unroll
      for (int r = 0; r < 4; r++) {
        const int row = lhi * 4 + r;
        Ps[w][row * 64 + ((ch ^ (row & 7)) << 3) + e] = (__bf16)p[n][r];
      }
    }
    asm volatile("s_waitcnt lgkmcnt(0)" ::: "memory");

    // O += P V
    __builtin_amdgcn_s_setprio(1);
#pragma unroll
    for (int kk = 0; kk < 2; kk++) {
      bf16x8 pa = *(const bf16x8*)&Ps[w][l15 * 64 + (kk ? c1 : c0)];
#pragma unroll
      for (int n = 0; n < 4; n++) {
        bf16x8 vb =
            *(const bf16x8*)&Vb[cur][(n * 16 + l15) * 64 + (kk ? c1 : c0)];
        o[n] = mfma16(pa, vb, o[n]);
      }
    }
    __builtin_amdgcn_s_setprio(0);
    cur ^= 1;
  }

  const long crow = (long)b * 1024 + q0;
  float rl[4];
#pragma unroll
  for (int r = 0; r < 4; r++) rl[r] = __builtin_amdgcn_rcpf(lrun[r]);
#pragma unroll
  for (int n = 0; n < 4; n++)
#pragma unroll
    for (int r = 0; r < 4; r++) {
      const float val = o[n][r] * rl[r];
      ctx[(crow + lhi * 4 + r) * 1024 + h * 64 + n * 16 + l15] = (__bf16)val;
    }
}

// ---------------------------------------------------------------------------
// 3-input residual LN: y = LN(a + b + c) * gamma + beta over D=1024.
// ---------------------------------------------------------------------------
template <int CB, int OB>
__global__ __launch_bounds__(256) void ln_fuse3(
    const float* __restrict__ a, const float* __restrict__ b,
    const void* __restrict__ c_, const float* __restrict__ gamma,
    const float* __restrict__ beta, float* __restrict__ outf,
    __bf16* __restrict__ outb)
{
  const int row = blockIdx.x;
  const int tid = threadIdx.x;
  const float4 va = ((const float4*)(a + (long)row * 1024))[tid];
  const float4 vb = ((const float4*)(b + (long)row * 1024))[tid];
  float c0, c1, c2, c3;
  if (CB) {
    const bf16x4 cv =
        *(const bf16x4*)((const __bf16*)c_ + (long)row * 1024 + tid * 4);
    c0 = (float)cv[0]; c1 = (float)cv[1]; c2 = (float)cv[2]; c3 = (float)cv[3];
  } else {
    const float4 vc = ((const float4*)((const float*)c_ + (long)row * 1024))[tid];
    c0 = vc.x; c1 = vc.y; c2 = vc.z; c3 = vc.w;
  }
  const float x0 = va.x + vb.x + c0, x1 = va.y + vb.y + c1,
              x2 = va.z + vb.z + c2, x3 = va.w + vb.w + c3;
  float sum = x0 + x1 + x2 + x3;
  float sq = x0 * x0 + x1 * x1 + x2 * x2 + x3 * x3;
#pragma unroll
  for (int off = 32; off; off >>= 1) {
    sum += __shfl_down(sum, off);
    sq += __shfl_down(sq, off);
  }
  __shared__ float red[8];
  const int w = tid >> 6;
  if ((tid & 63) == 0) { red[w] = sum; red[4 + w] = sq; }
  __syncthreads();
  sum = red[0] + red[1] + red[2] + red[3];
  sq = red[4] + red[5] + red[6] + red[7];
  const float mean = sum * (1.f / 1024.f);
  const float var = sq * (1.f / 1024.f) - mean * mean;
  const float inv = rsqrtf(var + 1e-6f);
  const float4 g = ((const float4*)gamma)[tid];
  const float4 be = ((const float4*)beta)[tid];
  const float y0 = (x0 - mean) * inv * g.x + be.x;
  const float y1 = (x1 - mean) * inv * g.y + be.y;
  const float y2 = (x2 - mean) * inv * g.z + be.z;
  const float y3 = (x3 - mean) * inv * g.w + be.w;
  if (OB) {
    __bf16* ob = outb + (long)row * 1024 + tid * 4;
    ob[0] = (__bf16)y0; ob[1] = (__bf16)y1;
    ob[2] = (__bf16)y2; ob[3] = (__bf16)y3;
  } else {
    float4 o4; o4.x = y0; o4.y = y1; o4.z = y2; o4.w = y3;
    ((float4*)(outf + (long)row * 1024))[tid] = o4;
  }
}

__global__ __launch_bounds__(256) void cast_bf16_kernel(
    const float* __restrict__ in, __bf16* __restrict__ out, int n4)
{
  const int i = blockIdx.x * 256 + threadIdx.x;
  if (i < n4) {
    const float4 v = ((const float4*)in)[i];
    __bf16* o = out + (long)i * 4;
    o[0] = (__bf16)v.x; o[1] = (__bf16)v.y;
    o[2] = (__bf16)v.z; o[3] = (__bf16)v.w;
  }
}

// in fp32 [R][C] (+batch) -> out bf16 [C][R]
__global__ __launch_bounds__(256) void transpose_cast_kernel(
    const float* __restrict__ in, __bf16* __restrict__ out, int R, int C,
    long ibs, long obs)
{
  __shared__ float t[32][33];
  const float* ip = in + (long)blockIdx.z * ibs;
  __bf16* op = out + (long)blockIdx.z * obs;
  const int c0 = blockIdx.x * 32, r0 = blockIdx.y * 32;
  const int tx = threadIdx.x & 31, ty = threadIdx.x >> 5;
#pragma unroll
  for (int i = 0; i < 32; i += 8)
    t[ty + i][tx] = ip[(long)(r0 + ty + i) * C + (c0 + tx)];
  __syncthreads();
#pragma unroll
  for (int i = 0; i < 32; i += 8)
    op[(long)(c0 + ty + i) * R + (r0 + tx)] = (__bf16)t[tx][ty + i];
}

extern "C" void kernel_launch(void* const* d_in, const int* in_sizes, int n_in,
                              void* d_out, int out_size, void* d_ws,
                              size_t ws_size, hipStream_t stream)
{
  const float* x   = (const float*)d_in[0];
  const float* Wq  = (const float*)d_in[1];
  const float* bq  = (const float*)d_in[2];
  const float* Wk  = (const float*)d_in[3];
  const float* bk  = (const float*)d_in[4];
  const float* Wv  = (const float*)d_in[5];
  const float* bv  = (const float*)d_in[6];
  const float* Wo  = (const float*)d_in[7];
  const float* bo  = (const float*)d_in[8];
  const float* W1  = (const float*)d_in[9];
  const float* b1  = (const float*)d_in[10];
  const float* W2  = (const float*)d_in[11];
  const float* b2  = (const float*)d_in[12];
  const float* g1  = (const float*)d_in[13];
  const float* be1 = (const float*)d_in[14];
  const float* g2  = (const float*)d_in[15];
  const float* be2 = (const float*)d_in[16];
  float* out = (float*)d_out;

  char* ws = (char*)d_ws;
  __bf16* wqkvT = (__bf16*)(ws);
  __bf16* woT   = (__bf16*)(ws + 6291456);
  __bf16* w1T   = (__bf16*)(ws + 8388608);
  __bf16* w2T   = (__bf16*)(ws + 16777216);
  __bf16* xbf   = (__bf16*)(ws + 25178112);
  __bf16* ctxb  = xbf;                        // xbf dead after QKV
  __bf16* qkv   = (__bf16*)(ws + 33566720);
  float*  mh_p1 = (float*)(ws + 33566720);    // qkv dead after attention
  __bf16* h1b   = (__bf16*)(ws + 50343936);
  __bf16* f1b   = (__bf16*)(ws + 58732544);   // [58.73, 92.29) MB
  float*  f2_p1 = (float*)(ws + 25178112);    // ctxb+mh_p1 dead by FFN2
  __bf16* vt    = (__bf16*)d_out;             // d_out free until Wo
  float*  mh_p0 = out;
  float*  f2_p0 = out;

  // --- pack weights/activations to bf16 (transposed: BT[N][K]) ---
  cast_bf16_kernel<<<4096, 256, 0, stream>>>(x, xbf, 1048576);
  transpose_cast_kernel<<<dim3(2, 32, 16), 256, 0, stream>>>(
      Wq, wqkvT, 1024, 64, 65536, 65536);
  transpose_cast_kernel<<<dim3(2, 32, 16), 256, 0, stream>>>(
      Wk, wqkvT + 1048576, 1024, 64, 65536, 65536);
  transpose_cast_kernel<<<dim3(2, 32, 16), 256, 0, stream>>>(
      Wv, wqkvT + 2097152, 1024, 64, 65536, 65536);
  transpose_cast_kernel<<<dim3(32, 32, 1), 256, 0, stream>>>(
      Wo, woT, 1024, 1024, 0, 0);
  transpose_cast_kernel<<<dim3(128, 32, 1), 256, 0, stream>>>(
      W1, w1T, 1024, 4096, 0, 0);
  transpose_cast_kernel<<<dim3(32, 128, 1), 256, 0, stream>>>(
      W2, w2T, 4096, 1024, 0, 0);

  // --- QKV projection (256^2 pipeline, scatter epilogue, fused bias) ---
  gemm256<0><<<dim3(12, 16), 512, 0, stream>>>(
      xbf, wqkvT, bq, bk, bv, qkv, 4096, 3072, 1024);

  // --- V transpose -> vt [bh][dk][s] (in d_out) ---
  vtrans_kernel<<<dim3(16, 64), 256, 0, stream>>>(qkv + 8388608, vt);

  // --- attention ---
  attn_kernel<<<dim3(16, 64), 256, 0, stream>>>(
      qkv, qkv + 4194304, vt, ctxb);

  // --- output projection, split-K2, 128x256 pipeline -> mh_p0 + mh_p1 ---
  gemm_ksplit<<<dim3(4, 32, 2), 512, 0, stream>>>(
      ctxb, woT, bo, mh_p0, mh_p1, 4096, 1024, 1024, 512);

  // --- LN1(mh_p0 + mh_p1 + x) -> h1b (bf16) ---
  ln_fuse3<0, 1><<<4096, 256, 0, stream>>>(
      mh_p0, mh_p1, x, g1, be1, nullptr, h1b);

  // --- FFN1 (256^2 pipeline, relu epilogue) ---
  gemm256<1><<<dim3(16, 16), 512, 0, stream>>>(
      h1b, w1T, b1, nullptr, nullptr, f1b, 4096, 4096, 1024);

  // --- FFN2, split-K2, 128x256 pipeline -> f2_p0 + f2_p1 ---
  gemm_ksplit<<<dim3(4, 32, 2), 512, 0, stream>>>(
      f1b, w2T, b2, f2_p0, f2_p1, 4096, 1024, 4096, 2048);

  // --- LN2(f2_p0 + f2_p1 + h1b) -> out ---
  ln_fuse3<1, 0><<<4096, 256, 0, stream>>>(
      f2_p0, f2_p1, h1b, g2, be2, out, nullptr);
}